// Round 1
// baseline (4975.554 us; speedup 1.0000x reference)
//
#include <hip/hip_runtime.h>
#include <math.h>

// Problem constants (setup_inputs): B=2, T=2048, E=2048, H=16, hd=128
#define TT 2048
#define EE 2048
#define NH 16
#define HD 128
#define MM 4096   // B*T

// ---------------------------------------------------------------------------
// Tiled fp32 GEMM: C[M,N] = A[M,K] @ B[K,N]. 128x128 tile, BK=16, 256 thr,
// 8x8 micro-tile per thread (rows contiguous, cols split tx*4 and tx*4+64).
// MODE 0: plain store to o0. MODE 1: scatter QKV cols into o0/o1/o2 [B,H,T,hd].
// ---------------------------------------------------------------------------
template <int MODE>
__global__ __launch_bounds__(256)
void gemm_k(const float* __restrict__ A, const float* __restrict__ B,
            float* __restrict__ o0, float* __restrict__ o1, float* __restrict__ o2,
            int M, int N, int K)
{
    __shared__ float As[16][132];   // stored transposed: As[k][m]
    __shared__ float Bs[16][132];   // natural: Bs[k][n]

    const int tid = threadIdx.x;
    const int tx = tid & 15;        // col group
    const int ty = tid >> 4;        // row group
    const int bm = blockIdx.y * 128;
    const int bn = blockIdx.x * 128;

    // global load mappings
    const int arow = tid >> 2;            // 0..63
    const int acq  = (tid & 3) << 2;      // k-quad 0/4/8/12
    const int brow = tid >> 5;            // 0..7
    const int bcol = (tid & 31) << 2;     // 0..124

    const float* Aptr = A + (size_t)(bm + arow) * K + acq;
    const float* Bptr = B + (size_t)brow * N + bn + bcol;

    float acc[8][8];
#pragma unroll
    for (int i = 0; i < 8; ++i)
#pragma unroll
        for (int j = 0; j < 8; ++j) acc[i][j] = 0.f;

    for (int kt = 0; kt < K; kt += 16) {
        float4 a0 = *(const float4*)(Aptr + kt);
        float4 a1 = *(const float4*)(Aptr + kt + (size_t)64 * K);
        float4 b0 = *(const float4*)(Bptr + (size_t)kt * N);
        float4 b1 = *(const float4*)(Bptr + (size_t)(kt + 8) * N);
        __syncthreads();   // previous iteration's readers done
        As[acq + 0][arow] = a0.x; As[acq + 1][arow] = a0.y;
        As[acq + 2][arow] = a0.z; As[acq + 3][arow] = a0.w;
        As[acq + 0][arow + 64] = a1.x; As[acq + 1][arow + 64] = a1.y;
        As[acq + 2][arow + 64] = a1.z; As[acq + 3][arow + 64] = a1.w;
        *(float4*)&Bs[brow][bcol]     = b0;
        *(float4*)&Bs[brow + 8][bcol] = b1;
        __syncthreads();
#pragma unroll
        for (int kk = 0; kk < 16; ++kk) {
            float4 a_0 = *(const float4*)&As[kk][ty * 8];
            float4 a_1 = *(const float4*)&As[kk][ty * 8 + 4];
            float4 b_0 = *(const float4*)&Bs[kk][tx * 4];
            float4 b_1 = *(const float4*)&Bs[kk][tx * 4 + 64];
            float ar[8] = {a_0.x, a_0.y, a_0.z, a_0.w, a_1.x, a_1.y, a_1.z, a_1.w};
            float br[8] = {b_0.x, b_0.y, b_0.z, b_0.w, b_1.x, b_1.y, b_1.z, b_1.w};
#pragma unroll
            for (int i = 0; i < 8; ++i)
#pragma unroll
                for (int j = 0; j < 8; ++j)
                    acc[i][j] = fmaf(ar[i], br[j], acc[i][j]);
        }
    }

    if (MODE == 0) {
#pragma unroll
        for (int i = 0; i < 8; ++i) {
            size_t rowoff = (size_t)(bm + ty * 8 + i) * N + bn;
            *(float4*)&o0[rowoff + tx * 4]      = make_float4(acc[i][0], acc[i][1], acc[i][2], acc[i][3]);
            *(float4*)&o0[rowoff + 64 + tx * 4] = make_float4(acc[i][4], acc[i][5], acc[i][6], acc[i][7]);
        }
    } else {
        // cols: n = bn + {tx*4+j, 64+tx*4+j}; n = sel*2048 + h*128 + d
        const int sel = bn >> 11;
        const int h   = (bn & 2047) >> 7;
        float* dst = (sel == 0) ? o0 : ((sel == 1) ? o1 : o2);
#pragma unroll
        for (int i = 0; i < 8; ++i) {
            int m = bm + ty * 8 + i;
            int b = m >> 11;          // m / T
            int t = m & 2047;         // m % T
            size_t base = (((size_t)b * NH + h) * TT + t) * HD;
            *(float4*)&dst[base + tx * 4]      = make_float4(acc[i][0], acc[i][1], acc[i][2], acc[i][3]);
            *(float4*)&dst[base + 64 + tx * 4] = make_float4(acc[i][4], acc[i][5], acc[i][6], acc[i][7]);
        }
    }
}

// ---------------------------------------------------------------------------
// In-place RoPE on q and k, layout [B,H,T,hd]. One thread per (row, pair j).
// out[j] = x[j]*cos(a) - x[j+64]*sin(a); out[j+64] = x[j+64]*cos(a) + x[j]*sin(a)
// a = t * 10000^(-2j/128)
// ---------------------------------------------------------------------------
__global__ __launch_bounds__(256)
void rope_kernel(float* __restrict__ q, float* __restrict__ k)
{
    int idx = blockIdx.x * 256 + threadIdx.x;   // B*H*T*64 total
    int j = idx & 63;
    int row = idx >> 6;        // b*H*T + h*T + t
    int t = row & (TT - 1);
    // inv_freq = exp(-(2j/128) * ln(10000))
    float inv = __expf((float)(2 * j) * (-9.210340371976184f / 128.0f));
    float ang = (float)t * inv;
    float s, c;
    sincosf(ang, &s, &c);
    size_t base = (size_t)row * HD;
    float q0 = q[base + j], q1 = q[base + j + 64];
    q[base + j]      = q0 * c - q1 * s;
    q[base + j + 64] = q1 * c + q0 * s;
    float k0 = k[base + j], k1 = k[base + j + 64];
    k[base + j]      = k0 * c - k1 * s;
    k[base + j + 64] = k1 * c + k0 * s;
}

// ---------------------------------------------------------------------------
// Flash-style causal attention, fp32. Grid (T/32, B*H). Block 256 thr.
// Thread (r = tid>>3, g = tid&7): owns query row r of the 32-row Q tile,
// S slots k = g+8i (bank-conflict-free Ks reads), O cols {32*jj + 4*g .. +3}.
// Online softmax (m, l per row, replicated across the 8-lane row group).
// Output written as [B, T, H*hd] so the proj GEMM reads it directly.
// ---------------------------------------------------------------------------
__global__ __launch_bounds__(256)
void attn_kernel(const float* __restrict__ Q, const float* __restrict__ K,
                 const float* __restrict__ V, const int* __restrict__ amask,
                 float* __restrict__ out)
{
    __shared__ float Qs[32][132];
    __shared__ float Ks[32][132];
    __shared__ float Vs[32][132];
    __shared__ float Ps[32][33];
    __shared__ int   mks[32];

    const int qt = blockIdx.x;
    const int bh = blockIdx.y;      // b*H + h
    const int b = bh >> 4;
    const int h = bh & 15;
    const int tid = threadIdx.x;
    const int r = tid >> 3;
    const int g = tid & 7;
    const int q_idx = qt * 32 + r;

    const size_t qbase = ((size_t)bh * TT + q_idx) * HD;
#pragma unroll
    for (int jj = 0; jj < 4; ++jj)
        *(float4*)&Qs[r][jj * 32 + g * 4] = *(const float4*)&Q[qbase + jj * 32 + g * 4];

    float m = -3.0e38f, l = 0.f;
    float o[16];
#pragma unroll
    for (int c = 0; c < 16; ++c) o[c] = 0.f;
    const float scale = 0.08838834764831843f;   // 128^-0.5

    const int ntiles = qt + 1;   // causal: only tiles up to the diagonal
    for (int kt = 0; kt < ntiles; ++kt) {
        __syncthreads();
        const size_t kbase = ((size_t)bh * TT + kt * 32 + r) * HD;
#pragma unroll
        for (int jj = 0; jj < 4; ++jj) {
            *(float4*)&Ks[r][jj * 32 + g * 4] = *(const float4*)&K[kbase + jj * 32 + g * 4];
            *(float4*)&Vs[r][jj * 32 + g * 4] = *(const float4*)&V[kbase + jj * 32 + g * 4];
        }
        if (tid < 32) mks[tid] = amask[b * TT + kt * 32 + tid];
        __syncthreads();

        // S[r][g+8i] = scale * Q[r]·K[g+8i], with causal + pad-key mask
        float s0 = 0.f, s1 = 0.f, s2 = 0.f, s3 = 0.f;
#pragma unroll
        for (int d = 0; d < 128; d += 4) {
            float4 qv = *(const float4*)&Qs[r][d];
            float4 k0 = *(const float4*)&Ks[g][d];
            float4 k1 = *(const float4*)&Ks[g + 8][d];
            float4 k2 = *(const float4*)&Ks[g + 16][d];
            float4 k3 = *(const float4*)&Ks[g + 24][d];
            s0 += qv.x * k0.x + qv.y * k0.y + qv.z * k0.z + qv.w * k0.w;
            s1 += qv.x * k1.x + qv.y * k1.y + qv.z * k1.z + qv.w * k1.w;
            s2 += qv.x * k2.x + qv.y * k2.y + qv.z * k2.z + qv.w * k2.w;
            s3 += qv.x * k3.x + qv.y * k3.y + qv.z * k3.z + qv.w * k3.w;
        }
        float sv[4] = {s0, s1, s2, s3};
        float x[4];
        float tmax = -3.0e38f;
#pragma unroll
        for (int i = 0; i < 4; ++i) {
            int kg = kt * 32 + g + 8 * i;
            float val = sv[i] * scale;
            if (kg > q_idx || mks[g + 8 * i] == 0) val = -1.0e9f;
            x[i] = val;
            tmax = fmaxf(tmax, val);
        }
#pragma unroll
        for (int off = 1; off < 8; off <<= 1)
            tmax = fmaxf(tmax, __shfl_xor(tmax, off, 64));

        float mnew = fmaxf(m, tmax);
        float corr = __expf(m - mnew);
        float psum = 0.f;
#pragma unroll
        for (int i = 0; i < 4; ++i) {
            float p = __expf(x[i] - mnew);
            Ps[r][g + 8 * i] = p;
            psum += p;
        }
#pragma unroll
        for (int off = 1; off < 8; off <<= 1)
            psum += __shfl_xor(psum, off, 64);
        l = l * corr + psum;
        m = mnew;
#pragma unroll
        for (int c = 0; c < 16; ++c) o[c] *= corr;
        __syncthreads();

        // O[r][c] += sum_k P[r][k] * V[k][c]
#pragma unroll 8
        for (int kk = 0; kk < 32; ++kk) {
            float p = Ps[r][kk];
#pragma unroll
            for (int jj = 0; jj < 4; ++jj) {
                float4 vv = *(const float4*)&Vs[kk][jj * 32 + g * 4];
                o[jj * 4 + 0] = fmaf(p, vv.x, o[jj * 4 + 0]);
                o[jj * 4 + 1] = fmaf(p, vv.y, o[jj * 4 + 1]);
                o[jj * 4 + 2] = fmaf(p, vv.z, o[jj * 4 + 2]);
                o[jj * 4 + 3] = fmaf(p, vv.w, o[jj * 4 + 3]);
            }
        }
    }

    float inv_l = (l > 0.f) ? (1.0f / l) : 0.f;
    const size_t obase = ((size_t)b * TT + q_idx) * EE + h * HD;
#pragma unroll
    for (int jj = 0; jj < 4; ++jj) {
        *(float4*)&out[obase + jj * 32 + g * 4] =
            make_float4(o[jj * 4 + 0] * inv_l, o[jj * 4 + 1] * inv_l,
                        o[jj * 4 + 2] * inv_l, o[jj * 4 + 3] * inv_l);
    }
}

// ---------------------------------------------------------------------------
extern "C" void kernel_launch(void* const* d_in, const int* in_sizes, int n_in,
                              void* d_out, int out_size, void* d_ws, size_t ws_size,
                              hipStream_t stream)
{
    (void)in_sizes; (void)n_in; (void)out_size; (void)ws_size;
    const float* x     = (const float*)d_in[0];
    const int*   amask = (const int*)d_in[1];
    const float* Wqkv  = (const float*)d_in[2];
    const float* Wproj = (const float*)d_in[3];
    float* out = (float*)d_out;

    const size_t buf = (size_t)MM * EE;   // 8M floats = 33.55 MB
    float* q    = (float*)d_ws;
    float* k    = q + buf;
    float* v    = k + buf;
    float* attn = v + buf;

    // 1) QKV GEMM [4096,2048]@[2048,6144] -> q/k/v in [B,H,T,hd]
    gemm_k<1><<<dim3(6144 / 128, MM / 128), 256, 0, stream>>>(
        x, Wqkv, q, k, v, MM, 3 * EE, EE);

    // 2) RoPE in-place on q and k
    rope_kernel<<<(MM * NH * 64) / 256, 256, 0, stream>>>(q, k);

    // 3) Causal attention -> attn in [B,T,E]
    attn_kernel<<<dim3(TT / 32, 2 * NH), 256, 0, stream>>>(q, k, v, amask, attn);

    // 4) Out projection [4096,2048]@[2048,2048] -> d_out
    gemm_k<0><<<dim3(EE / 128, MM / 128), 256, 0, stream>>>(
        attn, Wproj, out, nullptr, nullptr, MM, EE, EE);
}

// Round 4
// 2080.396 us; speedup vs baseline: 2.3916x; 2.3916x over previous
//
#include <hip/hip_runtime.h>
#include <math.h>

// Problem constants (setup_inputs): B=2, T=2048, E=2048, H=16, hd=128
#define TT 2048
#define EE 2048
#define NH 16
#define HD 128
#define MM 4096   // B*T

using f32x4  = __attribute__((ext_vector_type(4))) float;
using bf16x8 = __attribute__((ext_vector_type(8))) short;

#define MFMA16(a, b, c) __builtin_amdgcn_mfma_f32_16x16x32_bf16(a, b, c, 0, 0, 0)

// round-to-nearest-even fp32 -> bf16 (bit pattern in ushort)
__device__ __forceinline__ ushort bf_hi(float x) {
    uint u = __float_as_uint(x);
    uint r = (u + 0x7fffu + ((u >> 16) & 1u)) >> 16;
    return (ushort)r;
}
__device__ __forceinline__ float bf_f(ushort h) {
    return __uint_as_float(((uint)h) << 16);
}

// ---------------------------------------------------------------------------
// Tiled fp32 GEMM (unchanged from round 1): C[M,N] = A[M,K] @ B[K,N].
// MODE 0: plain store. MODE 1: scatter QKV cols into o0/o1/o2 [B,H,T,hd].
// ---------------------------------------------------------------------------
template <int MODE>
__global__ __launch_bounds__(256)
void gemm_k(const float* __restrict__ A, const float* __restrict__ B,
            float* __restrict__ o0, float* __restrict__ o1, float* __restrict__ o2,
            int M, int N, int K)
{
    __shared__ float As[16][132];   // transposed: As[k][m]
    __shared__ float Bs[16][132];   // natural: Bs[k][n]

    const int tid = threadIdx.x;
    const int tx = tid & 15;
    const int ty = tid >> 4;
    const int bm = blockIdx.y * 128;
    const int bn = blockIdx.x * 128;

    const int arow = tid >> 2;
    const int acq  = (tid & 3) << 2;
    const int brow = tid >> 5;
    const int bcol = (tid & 31) << 2;

    const float* Aptr = A + (size_t)(bm + arow) * K + acq;
    const float* Bptr = B + (size_t)brow * N + bn + bcol;

    float acc[8][8];
#pragma unroll
    for (int i = 0; i < 8; ++i)
#pragma unroll
        for (int j = 0; j < 8; ++j) acc[i][j] = 0.f;

    for (int kt = 0; kt < K; kt += 16) {
        float4 a0 = *(const float4*)(Aptr + kt);
        float4 a1 = *(const float4*)(Aptr + kt + (size_t)64 * K);
        float4 b0 = *(const float4*)(Bptr + (size_t)kt * N);
        float4 b1 = *(const float4*)(Bptr + (size_t)(kt + 8) * N);
        __syncthreads();
        As[acq + 0][arow] = a0.x; As[acq + 1][arow] = a0.y;
        As[acq + 2][arow] = a0.z; As[acq + 3][arow] = a0.w;
        As[acq + 0][arow + 64] = a1.x; As[acq + 1][arow + 64] = a1.y;
        As[acq + 2][arow + 64] = a1.z; As[acq + 3][arow + 64] = a1.w;
        *(float4*)&Bs[brow][bcol]     = b0;
        *(float4*)&Bs[brow + 8][bcol] = b1;
        __syncthreads();
#pragma unroll
        for (int kk = 0; kk < 16; ++kk) {
            float4 a_0 = *(const float4*)&As[kk][ty * 8];
            float4 a_1 = *(const float4*)&As[kk][ty * 8 + 4];
            float4 b_0 = *(const float4*)&Bs[kk][tx * 4];
            float4 b_1 = *(const float4*)&Bs[kk][tx * 4 + 64];
            float ar[8] = {a_0.x, a_0.y, a_0.z, a_0.w, a_1.x, a_1.y, a_1.z, a_1.w};
            float br[8] = {b_0.x, b_0.y, b_0.z, b_0.w, b_1.x, b_1.y, b_1.z, b_1.w};
#pragma unroll
            for (int i = 0; i < 8; ++i)
#pragma unroll
                for (int j = 0; j < 8; ++j)
                    acc[i][j] = fmaf(ar[i], br[j], acc[i][j]);
        }
    }

    if (MODE == 0) {
#pragma unroll
        for (int i = 0; i < 8; ++i) {
            size_t rowoff = (size_t)(bm + ty * 8 + i) * N + bn;
            *(float4*)&o0[rowoff + tx * 4]      = make_float4(acc[i][0], acc[i][1], acc[i][2], acc[i][3]);
            *(float4*)&o0[rowoff + 64 + tx * 4] = make_float4(acc[i][4], acc[i][5], acc[i][6], acc[i][7]);
        }
    } else {
        const int sel = bn >> 11;
        const int h   = (bn & 2047) >> 7;
        float* dst = (sel == 0) ? o0 : ((sel == 1) ? o1 : o2);
#pragma unroll
        for (int i = 0; i < 8; ++i) {
            int m = bm + ty * 8 + i;
            int b = m >> 11;
            int t = m & 2047;
            size_t base = (((size_t)b * NH + h) * TT + t) * HD;
            *(float4*)&dst[base + tx * 4]      = make_float4(acc[i][0], acc[i][1], acc[i][2], acc[i][3]);
            *(float4*)&dst[base + 64 + tx * 4] = make_float4(acc[i][4], acc[i][5], acc[i][6], acc[i][7]);
        }
    }
}

// ---------------------------------------------------------------------------
// In-place RoPE on q and k (unchanged from round 1).
// ---------------------------------------------------------------------------
__global__ __launch_bounds__(256)
void rope_kernel(float* __restrict__ q, float* __restrict__ k)
{
    int idx = blockIdx.x * 256 + threadIdx.x;
    int j = idx & 63;
    int row = idx >> 6;
    int t = row & (TT - 1);
    float inv = __expf((float)(2 * j) * (-9.210340371976184f / 128.0f));
    float ang = (float)t * inv;
    float s, c;
    sincosf(ang, &s, &c);
    size_t base = (size_t)row * HD;
    float q0 = q[base + j], q1 = q[base + j + 64];
    q[base + j]      = q0 * c - q1 * s;
    q[base + j + 64] = q1 * c + q0 * s;
    float k0 = k[base + j], k1 = k[base + j + 64];
    k[base + j]      = k0 * c - k1 * s;
    k[base + j + 64] = k1 * c + k0 * s;
}

// ---------------------------------------------------------------------------
// Transpose V [B,H,T,128] -> Vt [B,H,128,T] (fp32, LDS-tiled, coalesced).
// ---------------------------------------------------------------------------
__global__ __launch_bounds__(256)
void transpose_v(const float* __restrict__ v, float* __restrict__ vt)
{
    __shared__ float tile[32][33];
    const int bh = blockIdx.z;
    const int t0 = blockIdx.x * 32, d0 = blockIdx.y * 32;
    const int tx = threadIdx.x & 31, ty = threadIdx.x >> 5;   // 32 x 8
#pragma unroll
    for (int j = 0; j < 4; ++j)
        tile[ty + 8 * j][tx] = v[((size_t)bh * TT + t0 + ty + 8 * j) * HD + d0 + tx];
    __syncthreads();
#pragma unroll
    for (int j = 0; j < 4; ++j)
        vt[((size_t)bh * HD + d0 + ty + 8 * j) * TT + t0 + tx] = tile[tx][ty + 8 * j];
}

// ---------------------------------------------------------------------------
// MFMA flash attention, split-bf16 (~fp32 accuracy).
// Block: 256 thr = 4 waves; QBLK=64 (16 q-rows/wave), KVBLK=32.
// QK^T: S = Q K^T via mfma_16x16x32_bf16, 3 split terms. S layout:
//   row(q) = 4*(lane>>4)+reg, col(key) = lane&15.
// PV: O^T = Vt * P^T (A-frag = Vt rows, B-frag = P rows), 3 split terms.
//   O^T layout: row(dim) = 4*(lane>>4)+reg, col(q) = lane&15.
// LDS 16B-slot XOR swizzles keep ds_read_b128 near conflict-free.
// ---------------------------------------------------------------------------
__global__ __launch_bounds__(256, 2)
void attn_mfma(const float* __restrict__ Q, const float* __restrict__ K,
               const float* __restrict__ Vt, const int* __restrict__ am,
               float* __restrict__ out)
{
    __shared__ ushort KsH[32 * 128], KsL[32 * 128];     // [key][dim] bf16 hi/lo
    __shared__ ushort VtH[128 * 32], VtL[128 * 32];     // [dim][key] bf16 hi/lo
    __shared__ ushort PH[4][512], PL[4][512];           // per-wave P [16 q][32 key]
    __shared__ float  cor[4][16], lsum[4][16];

    const int tid  = threadIdx.x;
    const int wid  = tid >> 6;
    const int lane = tid & 63;
    const int lh   = lane >> 4;    // 0..3
    const int j16  = lane & 15;    // 0..15

    const int qt = (int)gridDim.x - 1 - (int)blockIdx.x;   // big blocks first
    const int bh = blockIdx.y;
    const int bb = bh >> 4, hh = bh & 15;
    const int q0 = qt * 64;
    const int ntiles = 2 * qt + 2;

    // ---- Q fragments (pre-scaled by hd^-0.5), bf16 hi/lo split, in regs ----
    const float scale = 0.08838834764831843f;
    bf16x8 qhf[4], qlf[4];
    {
        const float* qrow = Q + ((size_t)bh * TT + q0 + wid * 16 + j16) * HD;
#pragma unroll
        for (int kc = 0; kc < 4; ++kc) {
            float4 a = *(const float4*)(qrow + kc * 32 + lh * 8);
            float4 b = *(const float4*)(qrow + kc * 32 + lh * 8 + 4);
            float f[8] = {a.x, a.y, a.z, a.w, b.x, b.y, b.z, b.w};
#pragma unroll
            for (int e = 0; e < 8; ++e) {
                float x = f[e] * scale;
                ushort hv = bf_hi(x);
                ushort lv = bf_hi(x - bf_f(hv));
                qhf[kc][e] = (short)hv;
                qlf[kc][e] = (short)lv;
            }
        }
    }
    int qm[4];
#pragma unroll
    for (int r = 0; r < 4; ++r)
        qm[r] = am[bb * TT + q0 + wid * 16 + 4 * lh + r];

    float m_run[4] = {-3e38f, -3e38f, -3e38f, -3e38f};
    float l_run[4] = {0.f, 0.f, 0.f, 0.f};
    f32x4 acc_o[8];
#pragma unroll
    for (int dt = 0; dt < 8; ++dt)
#pragma unroll
        for (int e = 0; e < 4; ++e) acc_o[dt][e] = 0.f;

    for (int kt = 0; kt < ntiles; ++kt) {
        const int kv0 = kt * 32;
        const int km0 = am[bb * TT + kv0 + j16];
        const int km1 = am[bb * TT + kv0 + 16 + j16];

        __syncthreads();   // previous tile's LDS consumers done

        // ---- stage K tile [32 key][128 dim] fp32 -> bf16 hi/lo, swizzled ----
        {
            const int kr = tid >> 3, f = tid & 7;
            const float* kp = K + ((size_t)bh * TT + kv0 + kr) * HD + f * 16;
            float4 f0 = *(const float4*)(kp + 0);
            float4 f1 = *(const float4*)(kp + 4);
            float4 f2 = *(const float4*)(kp + 8);
            float4 f3 = *(const float4*)(kp + 12);
            float fv[16] = {f0.x, f0.y, f0.z, f0.w, f1.x, f1.y, f1.z, f1.w,
                            f2.x, f2.y, f2.z, f2.w, f3.x, f3.y, f3.z, f3.w};
            ushort hs[16], lo_[16];
#pragma unroll
            for (int e = 0; e < 16; ++e) {
                ushort hv = bf_hi(fv[e]);
                hs[e] = hv;
                lo_[e] = bf_hi(fv[e] - bf_f(hv));
            }
            const int s0 = (2 * f) ^ (kr & 7);
            const int s1 = (2 * f + 1) ^ (kr & 7);
            uint4 wh0, wh1, wl0, wl1;
            wh0.x = hs[0] | ((uint)hs[1] << 16);  wh0.y = hs[2] | ((uint)hs[3] << 16);
            wh0.z = hs[4] | ((uint)hs[5] << 16);  wh0.w = hs[6] | ((uint)hs[7] << 16);
            wh1.x = hs[8] | ((uint)hs[9] << 16);  wh1.y = hs[10] | ((uint)hs[11] << 16);
            wh1.z = hs[12] | ((uint)hs[13] << 16); wh1.w = hs[14] | ((uint)hs[15] << 16);
            wl0.x = lo_[0] | ((uint)lo_[1] << 16);  wl0.y = lo_[2] | ((uint)lo_[3] << 16);
            wl0.z = lo_[4] | ((uint)lo_[5] << 16);  wl0.w = lo_[6] | ((uint)lo_[7] << 16);
            wl1.x = lo_[8] | ((uint)lo_[9] << 16);  wl1.y = lo_[10] | ((uint)lo_[11] << 16);
            wl1.z = lo_[12] | ((uint)lo_[13] << 16); wl1.w = lo_[14] | ((uint)lo_[15] << 16);
            *(uint4*)&KsH[kr * 128 + s0 * 8] = wh0;
            *(uint4*)&KsH[kr * 128 + s1 * 8] = wh1;
            *(uint4*)&KsL[kr * 128 + s0 * 8] = wl0;
            *(uint4*)&KsL[kr * 128 + s1 * 8] = wl1;
        }
        // ---- stage Vt tile [128 dim][32 key] fp32 -> bf16 hi/lo, swizzled ----
        {
            const int f = tid & 7;
#pragma unroll
            for (int rr = 0; rr < 4; ++rr) {
                const int d = rr * 32 + (tid >> 3);
                const float* vp = Vt + ((size_t)bh * HD + d) * TT + kv0 + f * 4;
                float4 fv = *(const float4*)vp;
                float vals[4] = {fv.x, fv.y, fv.z, fv.w};
                ushort h4[4], l4[4];
#pragma unroll
                for (int e = 0; e < 4; ++e) {
                    ushort hv = bf_hi(vals[e]);
                    h4[e] = hv;
                    l4[e] = bf_hi(vals[e] - bf_f(hv));
                }
                const int sl = ((f >> 1) ^ ((d >> 1) & 3));
                const int off = d * 32 + sl * 8 + (f & 1) * 4;
                uint2 wh, wl;
                wh.x = h4[0] | ((uint)h4[1] << 16);  wh.y = h4[2] | ((uint)h4[3] << 16);
                wl.x = l4[0] | ((uint)l4[1] << 16);  wl.y = l4[2] | ((uint)l4[3] << 16);
                *(uint2*)&VtH[off] = wh;
                *(uint2*)&VtL[off] = wl;
            }
        }
        __syncthreads();   // staged tile visible

        // ---- QK^T: 3-term split-bf16 MFMA ----
        f32x4 s0v, s1v;
#pragma unroll
        for (int e = 0; e < 4; ++e) { s0v[e] = 0.f; s1v[e] = 0.f; }
#pragma unroll
        for (int kc = 0; kc < 4; ++kc) {
            const int sA = (((kc * 4 + lh) ^ (j16 & 7)) * 8);
            bf16x8 kh0 = *(const bf16x8*)&KsH[j16 * 128 + sA];
            bf16x8 kl0 = *(const bf16x8*)&KsL[j16 * 128 + sA];
            bf16x8 kh1 = *(const bf16x8*)&KsH[(16 + j16) * 128 + sA];
            bf16x8 kl1 = *(const bf16x8*)&KsL[(16 + j16) * 128 + sA];
            s0v = MFMA16(qhf[kc], kh0, s0v);
            s0v = MFMA16(qhf[kc], kl0, s0v);
            s0v = MFMA16(qlf[kc], kh0, s0v);
            s1v = MFMA16(qhf[kc], kh1, s1v);
            s1v = MFMA16(qhf[kc], kl1, s1v);
            s1v = MFMA16(qlf[kc], kh1, s1v);
        }

        // ---- mask + online softmax (per q-row = 4*lh + r) ----
        float p0[4], p1[4], corr[4];
#pragma unroll
        for (int r = 0; r < 4; ++r) {
            const int qg = q0 + wid * 16 + 4 * lh + r;
            float x0 = s0v[r], x1 = s1v[r];
            if ((kv0 + j16 > qg) | (km0 == 0) | (qm[r] == 0)) x0 = -1e9f;
            if ((kv0 + 16 + j16 > qg) | (km1 == 0) | (qm[r] == 0)) x1 = -1e9f;
            float rmax = fmaxf(x0, x1);
            rmax = fmaxf(rmax, __shfl_xor(rmax, 1));
            rmax = fmaxf(rmax, __shfl_xor(rmax, 2));
            rmax = fmaxf(rmax, __shfl_xor(rmax, 4));
            rmax = fmaxf(rmax, __shfl_xor(rmax, 8));
            float mnew = fmaxf(m_run[r], rmax);
            corr[r] = __expf(m_run[r] - mnew);
            m_run[r] = mnew;
            p0[r] = __expf(x0 - mnew);
            p1[r] = __expf(x1 - mnew);
            float ps = p0[r] + p1[r];
            ps += __shfl_xor(ps, 1);
            ps += __shfl_xor(ps, 2);
            ps += __shfl_xor(ps, 4);
            ps += __shfl_xor(ps, 8);
            l_run[r] = l_run[r] * corr[r] + ps;
        }

        // ---- P -> bf16 hi/lo into per-wave LDS (swizzled rows) ----
#pragma unroll
        for (int r = 0; r < 4; ++r) {
            const int q = 4 * lh + r;
            const int sw = (q >> 1) & 3;
            ushort h0 = bf_hi(p0[r]); ushort l0 = bf_hi(p0[r] - bf_f(h0));
            ushort h1 = bf_hi(p1[r]); ushort l1 = bf_hi(p1[r] - bf_f(h1));
            const int off0 = q * 32 + (((j16 >> 3) ^ sw) * 8) + (j16 & 7);
            const int off1 = q * 32 + ((((j16 >> 3) + 2) ^ sw) * 8) + (j16 & 7);
            PH[wid][off0] = h0; PL[wid][off0] = l0;
            PH[wid][off1] = h1; PL[wid][off1] = l1;
        }
        if (j16 == 0) {
            cor[wid][4 * lh + 0] = corr[0];
            cor[wid][4 * lh + 1] = corr[1];
            cor[wid][4 * lh + 2] = corr[2];
            cor[wid][4 * lh + 3] = corr[3];
        }

        // ---- rescale O^T (lane's q = j16) ----
        const float cq = cor[wid][j16];
#pragma unroll
        for (int dt = 0; dt < 8; ++dt)
#pragma unroll
            for (int e = 0; e < 4; ++e) acc_o[dt][e] *= cq;

        // ---- PV: O^T += Vt * P^T, 3-term split ----
        const int sP = ((lh ^ ((j16 >> 1) & 3)) * 8);
        bf16x8 pbh = *(const bf16x8*)&PH[wid][j16 * 32 + sP];
        bf16x8 pbl = *(const bf16x8*)&PL[wid][j16 * 32 + sP];
#pragma unroll
        for (int dt = 0; dt < 8; ++dt) {
            const int d = dt * 16 + j16;
            const int sV = ((lh ^ ((d >> 1) & 3)) * 8);
            bf16x8 vh = *(const bf16x8*)&VtH[d * 32 + sV];
            bf16x8 vl = *(const bf16x8*)&VtL[d * 32 + sV];
            acc_o[dt] = MFMA16(vh, pbh, acc_o[dt]);
            acc_o[dt] = MFMA16(vh, pbl, acc_o[dt]);
            acc_o[dt] = MFMA16(vl, pbh, acc_o[dt]);
        }
    }

    // ---- finalize: divide by l, store O (out layout [B,T,E]) ----
    if (j16 == 0) {
        lsum[wid][4 * lh + 0] = l_run[0];
        lsum[wid][4 * lh + 1] = l_run[1];
        lsum[wid][4 * lh + 2] = l_run[2];
        lsum[wid][4 * lh + 3] = l_run[3];
    }
    const float linv = 1.f / lsum[wid][j16];
    const int qg = q0 + wid * 16 + j16;
    float* orow = out + ((size_t)bb * TT + qg) * EE + hh * HD;
#pragma unroll
    for (int dt = 0; dt < 8; ++dt) {
        orow[dt * 16 + 4 * lh + 0] = acc_o[dt][0] * linv;
        orow[dt * 16 + 4 * lh + 1] = acc_o[dt][1] * linv;
        orow[dt * 16 + 4 * lh + 2] = acc_o[dt][2] * linv;
        orow[dt * 16 + 4 * lh + 3] = acc_o[dt][3] * linv;
    }
}

// ---------------------------------------------------------------------------
extern "C" void kernel_launch(void* const* d_in, const int* in_sizes, int n_in,
                              void* d_out, int out_size, void* d_ws, size_t ws_size,
                              hipStream_t stream)
{
    (void)in_sizes; (void)n_in; (void)out_size; (void)ws_size;
    const float* x     = (const float*)d_in[0];
    const int*   amask = (const int*)d_in[1];
    const float* Wqkv  = (const float*)d_in[2];
    const float* Wproj = (const float*)d_in[3];
    float* out = (float*)d_out;

    const size_t buf = (size_t)MM * EE;   // 8M floats = 32 MiB
    float* q    = (float*)d_ws;           // [0,32MiB)
    float* k    = q + buf;                // [32,64)
    float* v    = k + buf;                // [64,96)
    float* vt   = v + buf;                // [96,128)  Vt [B,H,128,T]
    float* attn = v;                      // alias: v dead after transpose

    // 1) QKV GEMM -> q/k/v in [B,H,T,hd] fp32
    gemm_k<1><<<dim3(6144 / 128, MM / 128), 256, 0, stream>>>(
        x, Wqkv, q, k, v, MM, 3 * EE, EE);

    // 2) RoPE in-place on q and k
    rope_kernel<<<(MM * NH * 64) / 256, 256, 0, stream>>>(q, k);

    // 3) Transpose V -> Vt [B,H,128,T]
    transpose_v<<<dim3(TT / 32, HD / 32, 2 * NH), 256, 0, stream>>>(v, vt);

    // 4) MFMA flash attention -> attn [B,T,E] fp32 (aliases v)
    attn_mfma<<<dim3(32, 2 * NH), 256, 0, stream>>>(q, k, vt, amask, attn);

    // 5) Out projection
    gemm_k<0><<<dim3(EE / 128, MM / 128), 256, 0, stream>>>(
        attn, Wproj, out, nullptr, nullptr, MM, EE, EE);
}

// Round 6
// 1031.057 us; speedup vs baseline: 4.8257x; 2.0177x over previous
//
#include <hip/hip_runtime.h>
#include <math.h>

// Problem constants (setup_inputs): B=2, T=2048, E=2048, H=16, hd=128
#define TT 2048
#define EE 2048
#define NH 16
#define HD 128
#define MM 4096   // B*T
#define GK 2048   // K dim of all new-path GEMMs

using f32x4  = __attribute__((ext_vector_type(4))) float;
using bf16x8 = __attribute__((ext_vector_type(8))) short;

#define MFMA16(a, b, c) __builtin_amdgcn_mfma_f32_16x16x32_bf16(a, b, c, 0, 0, 0)

// round-to-nearest-even fp32 -> bf16 (bit pattern in ushort)
__device__ __forceinline__ ushort bf_hi(float x) {
    uint u = __float_as_uint(x);
    uint r = (u + 0x7fffu + ((u >> 16) & 1u)) >> 16;
    return (ushort)r;
}
__device__ __forceinline__ float bf_f(ushort h) {
    return __uint_as_float(((uint)h) << 16);
}

// async global->LDS 16B: per-lane global src, wave-uniform LDS base + lane*16
__device__ __forceinline__ void gload16(const void* g, void* l) {
    __builtin_amdgcn_global_load_lds((const __attribute__((address_space(1))) void*)g,
                                     (__attribute__((address_space(3))) void*)l, 16, 0, 0);
}

// ---------------------------------------------------------------------------
//

// Fallback fp32 GEMM (round-4 proven). MODE 0 plain, MODE 1 QKV scatter.
// ---------------------------------------------------------------------------
template <int MODE>
__global__ __launch_bounds__(256)
void gemm_k(const float* __restrict__ A, const float* __restrict__ B,
            float* __restrict__ o0, float* __restrict__ o1, float* __restrict__ o2,
            int M, int N, int K)
{
    __shared__ float As[16][132];
    __shared__ float Bs[16][132];

    const int tid = threadIdx.x;
    const int tx = tid & 15;
    const int ty = tid >> 4;
    const int bm = blockIdx.y * 128;
    const int bn = blockIdx.x * 128;

    const int arow = tid >> 2;
    const int acq  = (tid & 3) << 2;
    const int brow = tid >> 5;
    const int bcol = (tid & 31) << 2;

    const float* Aptr = A + (size_t)(bm + arow) * K + acq;
    const float* Bptr = B + (size_t)brow * N + bn + bcol;

    float acc[8][8];
#pragma unroll
    for (int i = 0; i < 8; ++i)
#pragma unroll
        for (int j = 0; j < 8; ++j) acc[i][j] = 0.f;

    for (int kt = 0; kt < K; kt += 16) {
        float4 a0 = *(const float4*)(Aptr + kt);
        float4 a1 = *(const float4*)(Aptr + kt + (size_t)64 * K);
        float4 b0 = *(const float4*)(Bptr + (size_t)kt * N);
        float4 b1 = *(const float4*)(Bptr + (size_t)(kt + 8) * N);
        __syncthreads();
        As[acq + 0][arow] = a0.x; As[acq + 1][arow] = a0.y;
        As[acq + 2][arow] = a0.z; As[acq + 3][arow] = a0.w;
        As[acq + 0][arow + 64] = a1.x; As[acq + 1][arow + 64] = a1.y;
        As[acq + 2][arow + 64] = a1.z; As[acq + 3][arow + 64] = a1.w;
        *(float4*)&Bs[brow][bcol]     = b0;
        *(float4*)&Bs[brow + 8][bcol] = b1;
        __syncthreads();
#pragma unroll
        for (int kk = 0; kk < 16; ++kk) {
            float4 a_0 = *(const float4*)&As[kk][ty * 8];
            float4 a_1 = *(const float4*)&As[kk][ty * 8 + 4];
            float4 b_0 = *(const float4*)&Bs[kk][tx * 4];
            float4 b_1 = *(const float4*)&Bs[kk][tx * 4 + 64];
            float ar[8] = {a_0.x, a_0.y, a_0.z, a_0.w, a_1.x, a_1.y, a_1.z, a_1.w};
            float br[8] = {b_0.x, b_0.y, b_0.z, b_0.w, b_1.x, b_1.y, b_1.z, b_1.w};
#pragma unroll
            for (int i = 0; i < 8; ++i)
#pragma unroll
                for (int j = 0; j < 8; ++j)
                    acc[i][j] = fmaf(ar[i], br[j], acc[i][j]);
        }
    }

    if (MODE == 0) {
#pragma unroll
        for (int i = 0; i < 8; ++i) {
            size_t rowoff = (size_t)(bm + ty * 8 + i) * N + bn;
            *(float4*)&o0[rowoff + tx * 4]      = make_float4(acc[i][0], acc[i][1], acc[i][2], acc[i][3]);
            *(float4*)&o0[rowoff + 64 + tx * 4] = make_float4(acc[i][4], acc[i][5], acc[i][6], acc[i][7]);
        }
    } else {
        const int sel = bn >> 11;
        const int h   = (bn & 2047) >> 7;
        float* dst = (sel == 0) ? o0 : ((sel == 1) ? o1 : o2);
#pragma unroll
        for (int i = 0; i < 8; ++i) {
            int m = bm + ty * 8 + i;
            int b = m >> 11;
            int t = m & 2047;
            size_t base = (((size_t)b * NH + h) * TT + t) * HD;
            *(float4*)&dst[base + tx * 4]      = make_float4(acc[i][0], acc[i][1], acc[i][2], acc[i][3]);
            *(float4*)&dst[base + 64 + tx * 4] = make_float4(acc[i][4], acc[i][5], acc[i][6], acc[i][7]);
        }
    }
}

// ---------------------------------------------------------------------------
// split_x: fp32 -> bf16 hi/lo arrays (same layout). n elems, 4/thread.
// ---------------------------------------------------------------------------
__global__ __launch_bounds__(256)
void split_x(const float* __restrict__ x, ushort* __restrict__ xh,
             ushort* __restrict__ xl)
{
    int idx = (blockIdx.x * 256 + threadIdx.x) * 4;
    float4 v = *(const float4*)&x[idx];
    float f[4] = {v.x, v.y, v.z, v.w};
    ushort h[4], l[4];
#pragma unroll
    for (int e = 0; e < 4; ++e) {
        h[e] = bf_hi(f[e]);
        l[e] = bf_hi(f[e] - bf_f(h[e]));
    }
    *(ushort4*)&xh[idx] = make_ushort4(h[0], h[1], h[2], h[3]);
    *(ushort4*)&xl[idx] = make_ushort4(l[0], l[1], l[2], l[3]);
}

// ---------------------------------------------------------------------------
// tw_prep: W [2048 k][ldw cols] fp32, cols [c0,c0+2048) -> Wt_hi/lo [2048 n][2048 k] bf16
// ---------------------------------------------------------------------------
__global__ __launch_bounds__(256)
void tw_prep(const float* __restrict__ W, int ldw, int c0,
             ushort* __restrict__ th, ushort* __restrict__ tl)
{
    __shared__ float tile[32][33];
    const int k0 = blockIdx.x * 32, n0 = blockIdx.y * 32;
    const int tx = threadIdx.x & 31, ty = threadIdx.x >> 5;   // 32 x 8
#pragma unroll
    for (int j = 0; j < 4; ++j)
        tile[ty + 8 * j][tx] = W[(size_t)(k0 + ty + 8 * j) * ldw + c0 + n0 + tx];
    __syncthreads();
#pragma unroll
    for (int j = 0; j < 4; ++j) {
        float v = tile[tx][ty + 8 * j];           // = W[k0+tx][c0+n0+ty+8j]
        ushort h = bf_hi(v);
        ushort l = bf_hi(v - bf_f(h));
        size_t off = (size_t)(n0 + ty + 8 * j) * GK + k0 + tx;
        th[off] = h;
        tl[off] = l;
    }
}

// ---------------------------------------------------------------------------
// Split-bf16 MFMA GEMM: C[4096][2048] = A[4096][2048] x W[2048 n][2048 k]^T
// A given as Ah/Al bf16 [m][k]; W as Bh/Bl bf16 [n][k] (pre-transposed).
// 3-term split: Ah*Bh + Ah*Bl + Al*Bh (~fp32 accuracy).
// Tile 128x128, BK=32, 256 thr = 4 waves (2x2), wave tile 64x64.
// Staging: global_load_lds dwordx4, LDS linear, source granules pre-swizzled
// (o_logical = (g&3) ^ (row&3)) so frag ds_read_b128 is <=2-way.
// SCATTER 0: C[m][n] plain fp32. SCATTER 1: n=h*128+d -> [B,H,T,hd] fp32.
// ---------------------------------------------------------------------------
template <int SCATTER>
__global__ __launch_bounds__(256)
void gemm_bf16(const ushort* __restrict__ Ah, const ushort* __restrict__ Al,
               const ushort* __restrict__ Bh, const ushort* __restrict__ Bl,
               float* __restrict__ out)
{
    __shared__ ushort AhS[4096], AlS[4096], BhS[4096], BlS[4096];  // [128][32] each

    const int tid  = threadIdx.x;
    const int wid  = tid >> 6;
    const int lane = tid & 63;
    const int lh   = lane >> 4;
    const int j16  = lane & 15;
    const int wm   = wid >> 1, wn = wid & 1;
    const int bm   = blockIdx.y * 128, bn = blockIdx.x * 128;

    // staging: wave wid stages granules g = wid*128 + lane (+64)
    const int g0 = wid * 128 + lane;
    const int g1 = g0 + 64;
    const int r0 = g0 >> 2, o0 = (g0 & 3) ^ (r0 & 3);
    const int r1 = g1 >> 2, o1 = (g1 & 3) ^ (r1 & 3);
    const size_t sa0 = (size_t)(bm + r0) * GK + o0 * 8;
    const size_t sa1 = (size_t)(bm + r1) * GK + o1 * 8;
    const size_t sb0 = (size_t)(bn + r0) * GK + o0 * 8;
    const size_t sb1 = (size_t)(bn + r1) * GK + o1 * 8;
    const ushort* a0h = Ah + sa0; const ushort* a1h = Ah + sa1;
    const ushort* a0l = Al + sa0; const ushort* a1l = Al + sa1;
    const ushort* b0h = Bh + sb0; const ushort* b1h = Bh + sb1;
    const ushort* b0l = Bl + sb0; const ushort* b1l = Bl + sb1;
    const int lds0 = wid * 1024;          // ushort index of wave chunk 0
    const int lds1 = wid * 1024 + 512;

    // frag read offsets (ushort): row r, oct oo -> r*32 + (oo^(r&3))*8
    const int swz = (lh ^ (j16 & 3)) * 8;
    int offA[4], offB[4];
#pragma unroll
    for (int i = 0; i < 4; ++i) {
        offA[i] = (wm * 64 + i * 16 + j16) * 32 + swz;
        offB[i] = (wn * 64 + i * 16 + j16) * 32 + swz;
    }

    f32x4 acc[4][4];
#pragma unroll
    for (int i = 0; i < 4; ++i)
#pragma unroll
        for (int j = 0; j < 4; ++j)
#pragma unroll
            for (int e = 0; e < 4; ++e) acc[i][j][e] = 0.f;

    for (int kt = 0; kt < GK; kt += 32) {
        __syncthreads();   // previous tile's readers done
        gload16(a0h + kt, &AhS[lds0]);
        gload16(a1h + kt, &AhS[lds1]);
        gload16(a0l + kt, &AlS[lds0]);
        gload16(a1l + kt, &AlS[lds1]);
        gload16(b0h + kt, &BhS[lds0]);
        gload16(b1h + kt, &BhS[lds1]);
        gload16(b0l + kt, &BlS[lds0]);
        gload16(b1l + kt, &BlS[lds1]);
        __syncthreads();   // vmcnt(0) drained by compiler before barrier

        bf16x8 ah[4], al[4], bh[4], bl[4];
#pragma unroll
        for (int i = 0; i < 4; ++i) {
            ah[i] = *(const bf16x8*)&AhS[offA[i]];
            al[i] = *(const bf16x8*)&AlS[offA[i]];
            bh[i] = *(const bf16x8*)&BhS[offB[i]];
            bl[i] = *(const bf16x8*)&BlS[offB[i]];
        }
#pragma unroll
        for (int i = 0; i < 4; ++i)
#pragma unroll
            for (int j = 0; j < 4; ++j) {
                acc[i][j] = MFMA16(ah[i], bh[j], acc[i][j]);
                acc[i][j] = MFMA16(ah[i], bl[j], acc[i][j]);
                acc[i][j] = MFMA16(al[i], bh[j], acc[i][j]);
            }
    }

#pragma unroll
    for (int i = 0; i < 4; ++i)
#pragma unroll
        for (int j = 0; j < 4; ++j) {
            const int n = bn + wn * 64 + j * 16 + j16;
#pragma unroll
            for (int e = 0; e < 4; ++e) {
                const int m = bm + wm * 64 + i * 16 + 4 * lh + e;
                if (SCATTER) {
                    const int h = n >> 7, d = n & 127;
                    const int b = m >> 11, t = m & 2047;
                    out[(((size_t)b * NH + h) * TT + t) * HD + d] = acc[i][j][e];
                } else {
                    out[(size_t)m * EE + n] = acc[i][j][e];
                }
            }
        }
}

// ---------------------------------------------------------------------------
// In-place RoPE on q and k (unchanged).
// ---------------------------------------------------------------------------
__global__ __launch_bounds__(256)
void rope_kernel(float* __restrict__ q, float* __restrict__ k)
{
    int idx = blockIdx.x * 256 + threadIdx.x;
    int j = idx & 63;
    int row = idx >> 6;
    int t = row & (TT - 1);
    float inv = __expf((float)(2 * j) * (-9.210340371976184f / 128.0f));
    float ang = (float)t * inv;
    float s, c;
    sincosf(ang, &s, &c);
    size_t base = (size_t)row * HD;
    float q0 = q[base + j], q1 = q[base + j + 64];
    q[base + j]      = q0 * c - q1 * s;
    q[base + j + 64] = q1 * c + q0 * s;
    float k0 = k[base + j], k1 = k[base + j + 64];
    k[base + j]      = k0 * c - k1 * s;
    k[base + j + 64] = k1 * c + k0 * s;
}

// ---------------------------------------------------------------------------
// Transpose V [B,H,T,128] -> Vt [B,H,128,T] (unchanged).
// ---------------------------------------------------------------------------
__global__ __launch_bounds__(256)
void transpose_v(const float* __restrict__ v, float* __restrict__ vt)
{
    __shared__ float tile[32][33];
    const int bh = blockIdx.z;
    const int t0 = blockIdx.x * 32, d0 = blockIdx.y * 32;
    const int tx = threadIdx.x & 31, ty = threadIdx.x >> 5;
#pragma unroll
    for (int j = 0; j < 4; ++j)
        tile[ty + 8 * j][tx] = v[((size_t)bh * TT + t0 + ty + 8 * j) * HD + d0 + tx];
    __syncthreads();
#pragma unroll
    for (int j = 0; j < 4; ++j)
        vt[((size_t)bh * HD + d0 + ty + 8 * j) * TT + t0 + tx] = tile[tx][ty + 8 * j];
}

// ---------------------------------------------------------------------------
// MFMA flash attention, split-bf16 (validated round 4).
// OM 0: fp32 out [B,T,E]. OM 1: bf16 hi/lo out (feeds proj GEMM directly).
// ---------------------------------------------------------------------------
template <int OM>
__global__ __launch_bounds__(256, 2)
void attn_mfma(const float* __restrict__ Q, const float* __restrict__ K,
               const float* __restrict__ Vt, const int* __restrict__ am,
               float* __restrict__ outF, ushort* __restrict__ oh,
               ushort* __restrict__ ol)
{
    __shared__ ushort KsH[32 * 128], KsL[32 * 128];
    __shared__ ushort VtH[128 * 32], VtL[128 * 32];
    __shared__ ushort PH[4][512], PL[4][512];
    __shared__ float  cor[4][16], lsum[4][16];

    const int tid  = threadIdx.x;
    const int wid  = tid >> 6;
    const int lane = tid & 63;
    const int lh   = lane >> 4;
    const int j16  = lane & 15;

    const int qt = (int)gridDim.x - 1 - (int)blockIdx.x;
    const int bh = blockIdx.y;
    const int bb = bh >> 4, hh = bh & 15;
    const int q0 = qt * 64;
    const int ntiles = 2 * qt + 2;

    const float scale = 0.08838834764831843f;
    bf16x8 qhf[4], qlf[4];
    {
        const float* qrow = Q + ((size_t)bh * TT + q0 + wid * 16 + j16) * HD;
#pragma unroll
        for (int kc = 0; kc < 4; ++kc) {
            float4 a = *(const float4*)(qrow + kc * 32 + lh * 8);
            float4 b = *(const float4*)(qrow + kc * 32 + lh * 8 + 4);
            float f[8] = {a.x, a.y, a.z, a.w, b.x, b.y, b.z, b.w};
#pragma unroll
            for (int e = 0; e < 8; ++e) {
                float x = f[e] * scale;
                ushort hv = bf_hi(x);
                ushort lv = bf_hi(x - bf_f(hv));
                qhf[kc][e] = (short)hv;
                qlf[kc][e] = (short)lv;
            }
        }
    }
    int qm[4];
#pragma unroll
    for (int r = 0; r < 4; ++r)
        qm[r] = am[bb * TT + q0 + wid * 16 + 4 * lh + r];

    float m_run[4] = {-3e38f, -3e38f, -3e38f, -3e38f};
    float l_run[4] = {0.f, 0.f, 0.f, 0.f};
    f32x4 acc_o[8];
#pragma unroll
    for (int dt = 0; dt < 8; ++dt)
#pragma unroll
        for (int e = 0; e < 4; ++e) acc_o[dt][e] = 0.f;

    for (int kt = 0; kt < ntiles; ++kt) {
        const int kv0 = kt * 32;
        const int km0 = am[bb * TT + kv0 + j16];
        const int km1 = am[bb * TT + kv0 + 16 + j16];

        __syncthreads();

        {
            const int kr = tid >> 3, f = tid & 7;
            const float* kp = K + ((size_t)bh * TT + kv0 + kr) * HD + f * 16;
            float4 f0 = *(const float4*)(kp + 0);
            float4 f1 = *(const float4*)(kp + 4);
            float4 f2 = *(const float4*)(kp + 8);
            float4 f3 = *(const float4*)(kp + 12);
            float fv[16] = {f0.x, f0.y, f0.z, f0.w, f1.x, f1.y, f1.z, f1.w,
                            f2.x, f2.y, f2.z, f2.w, f3.x, f3.y, f3.z, f3.w};
            ushort hs[16], lo_[16];
#pragma unroll
            for (int e = 0; e < 16; ++e) {
                ushort hv = bf_hi(fv[e]);
                hs[e] = hv;
                lo_[e] = bf_hi(fv[e] - bf_f(hv));
            }
            const int s0 = (2 * f) ^ (kr & 7);
            const int s1 = (2 * f + 1) ^ (kr & 7);
            uint4 wh0, wh1, wl0, wl1;
            wh0.x = hs[0] | ((uint)hs[1] << 16);  wh0.y = hs[2] | ((uint)hs[3] << 16);
            wh0.z = hs[4] | ((uint)hs[5] << 16);  wh0.w = hs[6] | ((uint)hs[7] << 16);
            wh1.x = hs[8] | ((uint)hs[9] << 16);  wh1.y = hs[10] | ((uint)hs[11] << 16);
            wh1.z = hs[12] | ((uint)hs[13] << 16); wh1.w = hs[14] | ((uint)hs[15] << 16);
            wl0.x = lo_[0] | ((uint)lo_[1] << 16);  wl0.y = lo_[2] | ((uint)lo_[3] << 16);
            wl0.z = lo_[4] | ((uint)lo_[5] << 16);  wl0.w = lo_[6] | ((uint)lo_[7] << 16);
            wl1.x = lo_[8] | ((uint)lo_[9] << 16);  wl1.y = lo_[10] | ((uint)lo_[11] << 16);
            wl1.z = lo_[12] | ((uint)lo_[13] << 16); wl1.w = lo_[14] | ((uint)lo_[15] << 16);
            *(uint4*)&KsH[kr * 128 + s0 * 8] = wh0;
            *(uint4*)&KsH[kr * 128 + s1 * 8] = wh1;
            *(uint4*)&KsL[kr * 128 + s0 * 8] = wl0;
            *(uint4*)&KsL[kr * 128 + s1 * 8] = wl1;
        }
        {
            const int f = tid & 7;
#pragma unroll
            for (int rr = 0; rr < 4; ++rr) {
                const int d = rr * 32 + (tid >> 3);
                const float* vp = Vt + ((size_t)bh * HD + d) * TT + kv0 + f * 4;
                float4 fv = *(const float4*)vp;
                float vals[4] = {fv.x, fv.y, fv.z, fv.w};
                ushort h4[4], l4[4];
#pragma unroll
                for (int e = 0; e < 4; ++e) {
                    ushort hv = bf_hi(vals[e]);
                    h4[e] = hv;
                    l4[e] = bf_hi(vals[e] - bf_f(hv));
                }
                const int sl = ((f >> 1) ^ ((d >> 1) & 3));
                const int off = d * 32 + sl * 8 + (f & 1) * 4;
                uint2 wh, wl;
                wh.x = h4[0] | ((uint)h4[1] << 16);  wh.y = h4[2] | ((uint)h4[3] << 16);
                wl.x = l4[0] | ((uint)l4[1] << 16);  wl.y = l4[2] | ((uint)l4[3] << 16);
                *(uint2*)&VtH[off] = wh;
                *(uint2*)&VtL[off] = wl;
            }
        }
        __syncthreads();

        f32x4 s0v, s1v;
#pragma unroll
        for (int e = 0; e < 4; ++e) { s0v[e] = 0.f; s1v[e] = 0.f; }
#pragma unroll
        for (int kc = 0; kc < 4; ++kc) {
            const int sA = (((kc * 4 + lh) ^ (j16 & 7)) * 8);
            bf16x8 kh0 = *(const bf16x8*)&KsH[j16 * 128 + sA];
            bf16x8 kl0 = *(const bf16x8*)&KsL[j16 * 128 + sA];
            bf16x8 kh1 = *(const bf16x8*)&KsH[(16 + j16) * 128 + sA];
            bf16x8 kl1 = *(const bf16x8*)&KsL[(16 + j16) * 128 + sA];
            s0v = MFMA16(qhf[kc], kh0, s0v);
            s0v = MFMA16(qhf[kc], kl0, s0v);
            s0v = MFMA16(qlf[kc], kh0, s0v);
            s1v = MFMA16(qhf[kc], kh1, s1v);
            s1v = MFMA16(qhf[kc], kl1, s1v);
            s1v = MFMA16(qlf[kc], kh1, s1v);
        }

        float p0[4], p1[4], corr[4];
#pragma unroll
        for (int r = 0; r < 4; ++r) {
            const int qg = q0 + wid * 16 + 4 * lh + r;
            float x0 = s0v[r], x1 = s1v[r];
            if ((kv0 + j16 > qg) | (km0 == 0) | (qm[r] == 0)) x0 = -1e9f;
            if ((kv0 + 16 + j16 > qg) | (km1 == 0) | (qm[r] == 0)) x1 = -1e9f;
            float rmax = fmaxf(x0, x1);
            rmax = fmaxf(rmax, __shfl_xor(rmax, 1));
            rmax = fmaxf(rmax, __shfl_xor(rmax, 2));
            rmax = fmaxf(rmax, __shfl_xor(rmax, 4));
            rmax = fmaxf(rmax, __shfl_xor(rmax, 8));
            float mnew = fmaxf(m_run[r], rmax);
            corr[r] = __expf(m_run[r] - mnew);
            m_run[r] = mnew;
            p0[r] = __expf(x0 - mnew);
            p1[r] = __expf(x1 - mnew);
            float ps = p0[r] + p1[r];
            ps += __shfl_xor(ps, 1);
            ps += __shfl_xor(ps, 2);
            ps += __shfl_xor(ps, 4);
            ps += __shfl_xor(ps, 8);
            l_run[r] = l_run[r] * corr[r] + ps;
        }

#pragma unroll
        for (int r = 0; r < 4; ++r) {
            const int q = 4 * lh + r;
            const int sw = (q >> 1) & 3;
            ushort h0 = bf_hi(p0[r]); ushort l0 = bf_hi(p0[r] - bf_f(h0));
            ushort h1 = bf_hi(p1[r]); ushort l1 = bf_hi(p1[r] - bf_f(h1));
            const int off0 = q * 32 + (((j16 >> 3) ^ sw) * 8) + (j16 & 7);
            const int off1 = q * 32 + ((((j16 >> 3) + 2) ^ sw) * 8) + (j16 & 7);
            PH[wid][off0] = h0; PL[wid][off0] = l0;
            PH[wid][off1] = h1; PL[wid][off1] = l1;
        }
        if (j16 == 0) {
            cor[wid][4 * lh + 0] = corr[0];
            cor[wid][4 * lh + 1] = corr[1];
            cor[wid][4 * lh + 2] = corr[2];
            cor[wid][4 * lh + 3] = corr[3];
        }

        const float cq = cor[wid][j16];
#pragma unroll
        for (int dt = 0; dt < 8; ++dt)
#pragma unroll
            for (int e = 0; e < 4; ++e) acc_o[dt][e] *= cq;

        const int sP = ((lh ^ ((j16 >> 1) & 3)) * 8);
        bf16x8 pbh = *(const bf16x8*)&PH[wid][j16 * 32 + sP];
        bf16x8 pbl = *(const bf16x8*)&PL[wid][j16 * 32 + sP];
#pragma unroll
        for (int dt = 0; dt < 8; ++dt) {
            const int d = dt * 16 + j16;
            const int sV = ((lh ^ ((d >> 1) & 3)) * 8);
            bf16x8 vh = *(const bf16x8*)&VtH[d * 32 + sV];
            bf16x8 vl = *(const bf16x8*)&VtL[d * 32 + sV];
            acc_o[dt] = MFMA16(vh, pbh, acc_o[dt]);
            acc_o[dt] = MFMA16(vh, pbl, acc_o[dt]);
            acc_o[dt] = MFMA16(vl, pbh, acc_o[dt]);
        }
    }

    if (j16 == 0) {
        lsum[wid][4 * lh + 0] = l_run[0];
        lsum[wid][4 * lh + 1] = l_run[1];
        lsum[wid][4 * lh + 2] = l_run[2];
        lsum[wid][4 * lh + 3] = l_run[3];
    }
    const float linv = 1.f / lsum[wid][j16];
    const int qg = q0 + wid * 16 + j16;
    const size_t obase = ((size_t)bb * TT + qg) * EE + hh * HD;
#pragma unroll
    for (int dt = 0; dt < 8; ++dt) {
        if (OM == 0) {
            outF[obase + dt * 16 + 4 * lh + 0] = acc_o[dt][0] * linv;
            outF[obase + dt * 16 + 4 * lh + 1] = acc_o[dt][1] * linv;
            outF[obase + dt * 16 + 4 * lh + 2] = acc_o[dt][2] * linv;
            outF[obase + dt * 16 + 4 * lh + 3] = acc_o[dt][3] * linv;
        } else {
            ushort h[4], l[4];
#pragma unroll
            for (int e = 0; e < 4; ++e) {
                float v = acc_o[dt][e] * linv;
                h[e] = bf_hi(v);
                l[e] = bf_hi(v - bf_f(h[e]));
            }
            *(ushort4*)&oh[obase + dt * 16 + 4 * lh] = make_ushort4(h[0], h[1], h[2], h[3]);
            *(ushort4*)&ol[obase + dt * 16 + 4 * lh] = make_ushort4(l[0], l[1], l[2], l[3]);
        }
    }
}

// ---------------------------------------------------------------------------
extern "C" void kernel_launch(void* const* d_in, const int* in_sizes, int n_in,
                              void* d_out, int out_size, void* d_ws, size_t ws_size,
                              hipStream_t stream)
{
    (void)in_sizes; (void)n_in; (void)out_size;
    const float* x     = (const float*)d_in[0];
    const int*   amask = (const int*)d_in[1];
    const float* Wqkv  = (const float*)d_in[2];
    const float* Wproj = (const float*)d_in[3];
    float* out = (float*)d_out;

    char* ws = (char*)d_ws;
    const size_t MB = 1024 * 1024;
    float* q = (float*)(ws + 0 * MB);
    float* k = (float*)(ws + 32 * MB);
    float* v = (float*)(ws + 64 * MB);

    if (ws_size >= 144 * MB) {
        // ---- split-bf16 MFMA GEMM path (144 MB workspace schedule) ----
        ushort* ah  = (ushort*)(ws + 64 * MB);   // attn hi (aliases dead v)
        ushort* al  = (ushort*)(ws + 80 * MB);   // attn lo
        ushort* xh  = (ushort*)(ws + 96 * MB);
        ushort* xl  = (ushort*)(ws + 112 * MB);
        float*  vt  = (float*)(ws + 96 * MB);    // aliases dead xh/xl
        ushort* wth = (ushort*)(ws + 128 * MB);
        ushort* wtl = (ushort*)(ws + 136 * MB);

        // 1) x -> bf16 hi/lo
        split_x<<<(MM * EE) / (256 * 4), 256, 0, stream>>>(x, xh, xl);

        // 2) per-slice: transpose+split weight, then MFMA GEMM -> q/k/v
        float* qkv[3] = {q, k, v};
        for (int s = 0; s < 3; ++s) {
            tw_prep<<<dim3(GK / 32, EE / 32), 256, 0, stream>>>(
                Wqkv, 3 * EE, s * EE, wth, wtl);
            gemm_bf16<1><<<dim3(EE / 128, MM / 128), 256, 0, stream>>>(
                xh, xl, wth, wtl, qkv[s]);
        }

        // 3) RoPE
        rope_kernel<<<(MM * NH * 64) / 256, 256, 0, stream>>>(q, k);

        // 4) V -> Vt (x dead, reuse its slot)
        transpose_v<<<dim3(TT / 32, HD / 32, 2 * NH), 256, 0, stream>>>(v, vt);

        // 5) proj weight prep (Wqkv slice buffer reused)
        tw_prep<<<dim3(GK / 32, EE / 32), 256, 0, stream>>>(
            Wproj, EE, 0, wth, wtl);

        // 6) attention -> bf16 hi/lo (v dead, reuse its slot)
        attn_mfma<1><<<dim3(32, 2 * NH), 256, 0, stream>>>(
            q, k, vt, amask, nullptr, ah, al);

        // 7) out projection (MFMA)
        gemm_bf16<0><<<dim3(EE / 128, MM / 128), 256, 0, stream>>>(
            ah, al, wth, wtl, out);
    } else {
        // ---- fallback: round-4 proven path (128 MB) ----
        float* vt   = (float*)(ws + 96 * MB);
        float* attn = v;
        gemm_k<1><<<dim3(6144 / 128, MM / 128), 256, 0, stream>>>(
            x, Wqkv, q, k, v, MM, 3 * EE, EE);
        rope_kernel<<<(MM * NH * 64) / 256, 256, 0, stream>>>(q, k);
        transpose_v<<<dim3(TT / 32, HD / 32, 2 * NH), 256, 0, stream>>>(v, vt);
        attn_mfma<0><<<dim3(32, 2 * NH), 256, 0, stream>>>(
            q, k, vt, amask, attn, nullptr, nullptr);
        gemm_k<0><<<dim3(EE / 128, MM / 128), 256, 0, stream>>>(
            attn, Wproj, out, nullptr, nullptr, MM, EE, EE);
    }
}